// Round 1
// baseline (238.912 us; speedup 1.0000x reference)
//
#include <hip/hip_runtime.h>
#include <math.h>

#define BB 32
#define CC 256
#define HWW 4096

// ---------------- Kernel A: c_adj[b,c] = mean over HW ----------------
__global__ __launch_bounds__(256) void avgpool_kernel(const float* __restrict__ x,
                                                      float* __restrict__ c_adj) {
    int bc = blockIdx.x;                       // 0 .. B*C-1
    const float4* p4 = (const float4*)(x + (size_t)bc * HWW);
    int t = threadIdx.x;                       // 256 threads
    float sum = 0.f;
#pragma unroll
    for (int m = 0; m < 4; ++m) {
        float4 v = p4[t + 256 * m];
        sum += v.x + v.y + v.z + v.w;
    }
    // wave (64-lane) reduce
#pragma unroll
    for (int off = 32; off > 0; off >>= 1)
        sum += __shfl_down(sum, off, 64);
    __shared__ float partial[4];
    int wid = t >> 6, lane = t & 63;
    if (lane == 0) partial[wid] = sum;
    __syncthreads();
    if (t == 0) {
        float tot = partial[0] + partial[1] + partial[2] + partial[3];
        c_adj[bc] = tot * (1.0f / HWW);
    }
}

// ---------------- Kernel B: w[b,i,j] = adj[i,j] * s ----------------
__global__ __launch_bounds__(256) void weight_kernel(const float* __restrict__ c_adj,
                                                     const float* __restrict__ adj,
                                                     float* __restrict__ w) {
    int idx = blockIdx.x * 256 + threadIdx.x;  // B*C*C = 2M
    int b = idx >> 16;                         // C*C = 65536
    int rem = idx & 65535;
    int i = rem >> 8;
    int j = rem & 255;
    float ci = c_adj[b * CC + i];
    float cj = c_adj[b * CC + j];
    float d = cj - ci;                         // t1 - t2
    float s1 = fabsf(fabsf(1.f / (1.f + expf(-d)) - 0.5f) - 0.5f) * 2.f;
    float s2 = fabsf(fabsf(1.f / (1.f + expf(d)) - 0.5f) - 0.5f) * 2.f;  // transposed term
    float s = 0.5f * (s1 + s2);
    w[idx] = adj[i * CC + j] * s;
}

// ---------------- Kernel C: out[b,i,n] = sum_j w[b,i,j]*x[b,j,n]; *para; relu --------
#define BM 64
#define BN 64
#define BK 16
#define WPAD 68   // BM+4 keeps float4 alignment AND kills write bank conflicts

__global__ __launch_bounds__(256) void gemm_kernel(const float* __restrict__ w,
                                                   const float* __restrict__ x,
                                                   const float* __restrict__ para,
                                                   float* __restrict__ out) {
    int b  = blockIdx.z;
    int i0 = blockIdx.y * BM;
    int n0 = blockIdx.x * BN;
    const float* wB = w + (size_t)b * CC * CC;
    const float* xB = x + (size_t)b * CC * HWW;
    float* outB     = out + (size_t)b * CC * HWW;

    __shared__ float wT[BK][WPAD];   // transposed w tile: wT[k][i]
    __shared__ float xT[BK][BN];

    int t  = threadIdx.x;
    int tr = t >> 4, tc = t & 15;

    float acc[4][4] = {};

    for (int k0 = 0; k0 < CC; k0 += BK) {
        // stage w tile: 64 rows(i) x 16 (k); thread t loads float4 of k
        {
            int i  = t >> 2;
            int kq = (t & 3) * 4;
            float4 v = *(const float4*)&wB[(size_t)(i0 + i) * CC + k0 + kq];
            wT[kq + 0][i] = v.x;
            wT[kq + 1][i] = v.y;
            wT[kq + 2][i] = v.z;
            wT[kq + 3][i] = v.w;
        }
        // stage x tile: 16 rows(k) x 64 cols(n); thread t loads float4 of n
        {
            int k  = t >> 4;
            int nq = (t & 15) * 4;
            float4 v = *(const float4*)&xB[(size_t)(k0 + k) * HWW + n0 + nq];
            *(float4*)&xT[k][nq] = v;
        }
        __syncthreads();
#pragma unroll
        for (int k = 0; k < BK; ++k) {
            float wv[4], xv[4];
            *(float4*)wv = *(const float4*)&wT[k][tr * 4];
            *(float4*)xv = *(const float4*)&xT[k][tc * 4];
#pragma unroll
            for (int r = 0; r < 4; ++r)
#pragma unroll
                for (int q = 0; q < 4; ++q)
                    acc[r][q] = fmaf(wv[r], xv[q], acc[r][q]);
        }
        __syncthreads();
    }

    // epilogue: *para, relu, store
#pragma unroll
    for (int r = 0; r < 4; ++r) {
        int i = i0 + tr * 4 + r;
        int n = n0 + tc * 4;
        float4 pv = *(const float4*)&para[(size_t)i * HWW + n];
        float4 o;
        o.x = fmaxf(acc[r][0] * pv.x, 0.f);
        o.y = fmaxf(acc[r][1] * pv.y, 0.f);
        o.z = fmaxf(acc[r][2] * pv.z, 0.f);
        o.w = fmaxf(acc[r][3] * pv.w, 0.f);
        *(float4*)&outB[(size_t)i * HWW + n] = o;
    }
}

extern "C" void kernel_launch(void* const* d_in, const int* in_sizes, int n_in,
                              void* d_out, int out_size, void* d_ws, size_t ws_size,
                              hipStream_t stream) {
    const float* x    = (const float*)d_in[0];   // [32,256,64,64]
    const float* adj  = (const float*)d_in[1];   // [256,256]
    const float* para = (const float*)d_in[2];   // [1,256,64,64]
    float* out = (float*)d_out;

    float* c_adj = (float*)d_ws;                         // 8192 floats
    float* w     = (float*)d_ws + (BB * CC);             // 2M floats (8 MB)

    // A: avg pool
    avgpool_kernel<<<BB * CC, 256, 0, stream>>>(x, c_adj);
    // B: similarity weights
    weight_kernel<<<(BB * CC * CC) / 256, 256, 0, stream>>>(c_adj, adj, w);
    // C: batched GEMM + para + relu
    dim3 grid(HWW / BN, CC / BM, BB);
    gemm_kernel<<<grid, 256, 0, stream>>>(w, x, para, out);
}

// Round 3
// 107.877 us; speedup vs baseline: 2.2147x; 2.2147x over previous
//
#include <hip/hip_runtime.h>
#include <math.h>

#define BB 32
#define CC 256
#define HWW 4096

typedef unsigned short u16;
typedef unsigned int u32;

typedef __attribute__((ext_vector_type(8))) short bf16x8;
typedef __attribute__((ext_vector_type(4))) float f32x4;

__device__ inline u16 f2bf(float f) {
    u32 u = __float_as_uint(f);
    u32 r = (u + 0x7fff + ((u >> 16) & 1)) >> 16;   // RNE
    return (u16)r;
}

// ================= Kernel A: fused avg-pool partial sums + transpose x -> xT[b][n][k] bf16

__global__ __launch_bounds__(256) void pool_transpose_kernel(const float* __restrict__ x,
                                                             u16* __restrict__ xT,
                                                             float* __restrict__ csum) {
    int b  = blockIdx.z;
    int c0 = blockIdx.y * 64;
    int h0 = blockIdx.x * 64;
    const float* xB = x + (size_t)b * CC * HWW;

    __shared__ float tile[64][65];
    int t  = threadIdx.x;
    int cl = t >> 4;            // 0..15
    int h4 = (t & 15) * 4;

#pragma unroll
    for (int m = 0; m < 4; ++m) {
        int c = cl + 16 * m;
        float4 v = *(const float4*)&xB[(size_t)(c0 + c) * HWW + h0 + h4];
        tile[c][h4 + 0] = v.x;
        tile[c][h4 + 1] = v.y;
        tile[c][h4 + 2] = v.z;
        tile[c][h4 + 3] = v.w;
        float s = v.x + v.y + v.z + v.w;
#pragma unroll
        for (int off = 8; off > 0; off >>= 1)
            s += __shfl_down(s, off, 16);
        if ((t & 15) == 0)
            atomicAdd(&csum[b * CC + c0 + c], s);
    }
    __syncthreads();

    int hl = t >> 2;            // 0..63
    int cq = (t & 3) * 16;      // 0,16,32,48
    u32 p0 = (u32)f2bf(tile[cq + 0][hl]) | ((u32)f2bf(tile[cq + 1][hl]) << 16);
    u32 p1 = (u32)f2bf(tile[cq + 2][hl]) | ((u32)f2bf(tile[cq + 3][hl]) << 16);
    u32 p2 = (u32)f2bf(tile[cq + 4][hl]) | ((u32)f2bf(tile[cq + 5][hl]) << 16);
    u32 p3 = (u32)f2bf(tile[cq + 6][hl]) | ((u32)f2bf(tile[cq + 7][hl]) << 16);
    u32 p4 = (u32)f2bf(tile[cq + 8][hl]) | ((u32)f2bf(tile[cq + 9][hl]) << 16);
    u32 p5 = (u32)f2bf(tile[cq +10][hl]) | ((u32)f2bf(tile[cq +11][hl]) << 16);
    u32 p6 = (u32)f2bf(tile[cq +12][hl]) | ((u32)f2bf(tile[cq +13][hl]) << 16);
    u32 p7 = (u32)f2bf(tile[cq +14][hl]) | ((u32)f2bf(tile[cq +15][hl]) << 16);
    u16* dst = xT + ((size_t)b * HWW + h0 + hl) * CC + c0 + cq;
    *(uint4*)(dst)     = make_uint4(p0, p1, p2, p3);
    *(uint4*)(dst + 8) = make_uint4(p4, p5, p6, p7);
}

// ================= Kernel B: w_bf16[b,i,j] = bf16( adj[i,j] * s )

__global__ __launch_bounds__(256) void weight_bf16_kernel(const float* __restrict__ csum,
                                                          const float* __restrict__ adj,
                                                          u16* __restrict__ wb) {
    int idx = blockIdx.x * 256 + threadIdx.x;
    int b = idx >> 16;
    int rem = idx & 65535;
    int i = rem >> 8;
    int j = rem & 255;
    float ci = csum[b * CC + i] * (1.0f / HWW);
    float cj = csum[b * CC + j] * (1.0f / HWW);
    float d = cj - ci;
    float s1 = fabsf(fabsf(1.f / (1.f + expf(-d)) - 0.5f) - 0.5f) * 2.f;
    float s2 = fabsf(fabsf(1.f / (1.f + expf(d)) - 0.5f) - 0.5f) * 2.f;
    float s = 0.5f * (s1 + s2);
    wb[idx] = f2bf(adj[i * CC + j] * s);
}

// ================= Kernel C: MFMA GEMM + para + relu
// Tile 128x128, BK=32, 4 waves (2x2), each wave 64x64 via 4x4 frags of 16x16x32.
// LDS row = 32 bf16 (four 16B chunks). Swizzle: chunk ^= (row>>1)&3  (bijective in-row).
#define GBM 128
#define GBN 128
#define GBK 32

__global__ __launch_bounds__(256) void mfma_gemm_kernel(const u16* __restrict__ wb,
                                                        const u16* __restrict__ xT,
                                                        const float* __restrict__ para,
                                                        float* __restrict__ out) {
    int b  = blockIdx.z;
    int i0 = blockIdx.y * GBM;
    int n0 = blockIdx.x * GBN;
    const u16* wB = wb + (size_t)b * CC * CC;     // [i][k], k contiguous
    const u16* xB = xT + (size_t)b * HWW * CC;    // [n][k], k contiguous

    __shared__ u16 lds[2][2][4096];               // [buf][A/B][128 rows x 32 k]

    int t    = threadIdx.x;
    int lane = t & 63;
    int wid  = t >> 6;
    int wr   = wid >> 1;
    int wc   = wid & 1;

    f32x4 acc[4][4] = {};

    // staging: thread t covers rows r0 and r0+64, 16B chunk c0q
    int r0  = t >> 2;          // 0..63
    int c0q = t & 3;
    int cs  = c0q ^ ((r0 >> 1) & 3);              // swizzled chunk (same key for r0+64)
    int e0 = r0 * 32 + 8 * cs;
    int e1 = (r0 + 64) * 32 + 8 * cs;

    const u16* gA0 = wB + (size_t)(i0 + r0) * CC + 8 * c0q;
    const u16* gA1 = wB + (size_t)(i0 + r0 + 64) * CC + 8 * c0q;
    const u16* gB0 = xB + (size_t)(n0 + r0) * CC + 8 * c0q;
    const u16* gB1 = xB + (size_t)(n0 + r0 + 64) * CC + 8 * c0q;

    uint4 ra0, ra1, rb0, rb1;

#define LOADT(kk) { ra0 = *(const uint4*)(gA0 + (kk)); ra1 = *(const uint4*)(gA1 + (kk)); \
                    rb0 = *(const uint4*)(gB0 + (kk)); rb1 = *(const uint4*)(gB1 + (kk)); }
#define STORET(bf) { *(uint4*)&lds[bf][0][e0] = ra0; *(uint4*)&lds[bf][0][e1] = ra1; \
                     *(uint4*)&lds[bf][1][e0] = rb0; *(uint4*)&lds[bf][1][e1] = rb1; }

    LOADT(0);
    STORET(0);
    __syncthreads();

    int lrow = lane & 15;
    int kc   = lane >> 4;                 // lane's 8-elem k-chunk index (0..3)
    int swz  = (lrow >> 1) & 3;           // (row>>1)&3 — row = ...16*m + lrow, m*16>>1 ≡ 0 mod 4

#pragma unroll 1
    for (int kt = 0; kt < 8; ++kt) {
        int cur = kt & 1;
        if (kt < 7) LOADT((kt + 1) * GBK);

        bf16x8 af[4], bfr[4];
#pragma unroll
        for (int m = 0; m < 4; ++m) {
            int row = wr * 64 + m * 16 + lrow;
            af[m] = *(bf16x8*)&lds[cur][0][row * 32 + 8 * (kc ^ swz)];
        }
#pragma unroll
        for (int q = 0; q < 4; ++q) {
            int row = wc * 64 + q * 16 + lrow;
            bfr[q] = *(bf16x8*)&lds[cur][1][row * 32 + 8 * (kc ^ swz)];
        }
#pragma unroll
        for (int m = 0; m < 4; ++m)
#pragma unroll
            for (int q = 0; q < 4; ++q)
                acc[m][q] = __builtin_amdgcn_mfma_f32_16x16x32_bf16(af[m], bfr[q], acc[m][q], 0, 0, 0);

        if (kt < 7) STORET(cur ^ 1);
        __syncthreads();
    }
#undef LOADT
#undef STORET

    // epilogue: D mapping col=lane&15, row=4*(lane>>4)+r  [m89-verified]
    int dcol = lane & 15;
    int drow = 4 * (lane >> 4);
#pragma unroll
    for (int m = 0; m < 4; ++m) {
#pragma unroll
        for (int q = 0; q < 4; ++q) {
            int i = i0 + wr * 64 + m * 16 + drow;
            int n = n0 + wc * 64 + q * 16 + dcol;
#pragma unroll
            for (int r = 0; r < 4; ++r) {
                float pv = para[(size_t)(i + r) * HWW + n];
                float o = acc[m][q][r] * pv;
                out[((size_t)b * CC + i + r) * HWW + n] = fmaxf(o, 0.f);
            }
        }
    }
}

// ================= FALLBACK (fp32 path, used if ws too small) =================

__global__ __launch_bounds__(256) void avgpool_kernel(const float* __restrict__ x,
                                                      float* __restrict__ c_adj) {
    int bc = blockIdx.x;
    const float4* p4 = (const float4*)(x + (size_t)bc * HWW);
    int t = threadIdx.x;
    float sum = 0.f;
#pragma unroll
    for (int m = 0; m < 4; ++m) {
        float4 v = p4[t + 256 * m];
        sum += v.x + v.y + v.z + v.w;
    }
#pragma unroll
    for (int off = 32; off > 0; off >>= 1)
        sum += __shfl_down(sum, off, 64);
    __shared__ float partial[4];
    int wid = t >> 6, lane = t & 63;
    if (lane == 0) partial[wid] = sum;
    __syncthreads();
    if (t == 0)
        c_adj[bc] = (partial[0] + partial[1] + partial[2] + partial[3]) * (1.0f / HWW);
}

__global__ __launch_bounds__(256) void weight_kernel(const float* __restrict__ c_adj,
                                                     const float* __restrict__ adj,
                                                     float* __restrict__ w) {
    int idx = blockIdx.x * 256 + threadIdx.x;
    int b = idx >> 16, rem = idx & 65535, i = rem >> 8, j = rem & 255;
    float ci = c_adj[b * CC + i], cj = c_adj[b * CC + j];
    float d = cj - ci;
    float s1 = fabsf(fabsf(1.f / (1.f + expf(-d)) - 0.5f) - 0.5f) * 2.f;
    float s2 = fabsf(fabsf(1.f / (1.f + expf(d)) - 0.5f) - 0.5f) * 2.f;
    w[idx] = adj[i * CC + j] * 0.5f * (s1 + s2);
}

#define BM 64
#define BN 64
#define BK 16
__global__ __launch_bounds__(256) void gemm_kernel(const float* __restrict__ w,
                                                   const float* __restrict__ x,
                                                   const float* __restrict__ para,
                                                   float* __restrict__ out) {
    int b = blockIdx.z, i0 = blockIdx.y * BM, n0 = blockIdx.x * BN;
    const float* wB = w + (size_t)b * CC * CC;
    const float* xB = x + (size_t)b * CC * HWW;
    float* outB = out + (size_t)b * CC * HWW;
    __shared__ float wT[BK][68];
    __shared__ float xS[BK][BN];
    int t = threadIdx.x, tr = t >> 4, tc = t & 15;
    float acc[4][4] = {};
    for (int k0 = 0; k0 < CC; k0 += BK) {
        {
            int i = t >> 2, kq = (t & 3) * 4;
            float4 v = *(const float4*)&wB[(size_t)(i0 + i) * CC + k0 + kq];
            wT[kq + 0][i] = v.x; wT[kq + 1][i] = v.y; wT[kq + 2][i] = v.z; wT[kq + 3][i] = v.w;
        }
        {
            int k = t >> 4, nq = (t & 15) * 4;
            *(float4*)&xS[k][nq] = *(const float4*)&xB[(size_t)(k0 + k) * HWW + n0 + nq];
        }
        __syncthreads();
#pragma unroll
        for (int k = 0; k < BK; ++k) {
            float wv[4], xv[4];
            *(float4*)wv = *(const float4*)&wT[k][tr * 4];
            *(float4*)xv = *(const float4*)&xS[k][tc * 4];
#pragma unroll
            for (int r = 0; r < 4; ++r)
#pragma unroll
                for (int q = 0; q < 4; ++q)
                    acc[r][q] = fmaf(wv[r], xv[q], acc[r][q]);
        }
        __syncthreads();
    }
#pragma unroll
    for (int r = 0; r < 4; ++r) {
        int i = i0 + tr * 4 + r, n = n0 + tc * 4;
        float4 pv = *(const float4*)&para[(size_t)i * HWW + n];
        float4 o;
        o.x = fmaxf(acc[r][0] * pv.x, 0.f);
        o.y = fmaxf(acc[r][1] * pv.y, 0.f);
        o.z = fmaxf(acc[r][2] * pv.z, 0.f);
        o.w = fmaxf(acc[r][3] * pv.w, 0.f);
        *(float4*)&outB[(size_t)i * HWW + n] = o;
    }
}

// ================= launch =================

extern "C" void kernel_launch(void* const* d_in, const int* in_sizes, int n_in,
                              void* d_out, int out_size, void* d_ws, size_t ws_size,
                              hipStream_t stream) {
    const float* x    = (const float*)d_in[0];
    const float* adj  = (const float*)d_in[1];
    const float* para = (const float*)d_in[2];
    float* out = (float*)d_out;

    const size_t XT_BYTES = (size_t)BB * HWW * CC * 2;       // 67,108,864
    const size_t WB_BYTES = (size_t)BB * CC * CC * 2;        //  4,194,304
    const size_t CS_BYTES = (size_t)BB * CC * 4;             //     32,768
    const size_t REQ = XT_BYTES + WB_BYTES + CS_BYTES;

    if (ws_size >= REQ) {
        u16*   xT   = (u16*)d_ws;
        u16*   wbuf = (u16*)((char*)d_ws + XT_BYTES);
        float* csum = (float*)((char*)d_ws + XT_BYTES + WB_BYTES);

        hipMemsetAsync(csum, 0, CS_BYTES, stream);
        dim3 gA(HWW / 64, CC / 64, BB);
        pool_transpose_kernel<<<gA, 256, 0, stream>>>(x, xT, csum);
        weight_bf16_kernel<<<(BB * CC * CC) / 256, 256, 0, stream>>>(csum, adj, wbuf);
        dim3 gC(HWW / GBN, CC / GBM, BB);
        mfma_gemm_kernel<<<gC, 256, 0, stream>>>(wbuf, xT, para, out);
    } else {
        float* c_adj = (float*)d_ws;
        float* w     = (float*)d_ws + (BB * CC);
        avgpool_kernel<<<BB * CC, 256, 0, stream>>>(x, c_adj);
        weight_kernel<<<(BB * CC * CC) / 256, 256, 0, stream>>>(c_adj, adj, w);
        dim3 grid(HWW / BN, CC / BM, BB);
        gemm_kernel<<<grid, 256, 0, stream>>>(w, x, para, out);
    }
}

// Round 4
// 96.762 us; speedup vs baseline: 2.4691x; 1.1149x over previous
//
#include <hip/hip_runtime.h>
#include <math.h>

#define BB 32
#define CC 256
#define HWW 4096

typedef unsigned short u16;
typedef unsigned int u32;

typedef __attribute__((ext_vector_type(8))) short bf16x8;
typedef __attribute__((ext_vector_type(4))) float f32x4;

__device__ inline u16 f2bf(float f) {
    u32 u = __float_as_uint(f);
    u32 r = (u + 0x7fff + ((u >> 16) & 1)) >> 16;   // RNE
    return (u16)r;
}

// ========== Kernel A: avg-pool partials + transpose x -> xT[b][n][k] bf16 ==========

__global__ __launch_bounds__(256) void pool_transpose_kernel(const float* __restrict__ x,
                                                             u16* __restrict__ xT,
                                                             float* __restrict__ partial) {
    int b  = blockIdx.z;
    int c0 = blockIdx.y * 64;
    int h0 = blockIdx.x * 64;
    const float* xB = x + (size_t)b * CC * HWW;

    __shared__ float tile[64][65];
    __shared__ float psum[64];
    int t  = threadIdx.x;
    int cl = t >> 4;            // 0..15
    int h4 = (t & 15) * 4;

#pragma unroll
    for (int m = 0; m < 4; ++m) {
        int c = cl + 16 * m;
        float4 v = *(const float4*)&xB[(size_t)(c0 + c) * HWW + h0 + h4];
        tile[c][h4 + 0] = v.x;
        tile[c][h4 + 1] = v.y;
        tile[c][h4 + 2] = v.z;
        tile[c][h4 + 3] = v.w;
        float s = v.x + v.y + v.z + v.w;
#pragma unroll
        for (int off = 8; off > 0; off >>= 1)
            s += __shfl_down(s, off, 16);
        if ((t & 15) == 0) psum[c] = s;
    }
    __syncthreads();

    // per-block row sums -> partial[b][hx][c]  (coalesced 256B store)
    if (t < 64)
        partial[((size_t)b * 64 + blockIdx.x) * CC + c0 + t] = psum[t];

    // transposed bf16 write
    int hl = t >> 2;            // 0..63
    int cq = (t & 3) * 16;      // 0,16,32,48
    u32 p0 = (u32)f2bf(tile[cq + 0][hl]) | ((u32)f2bf(tile[cq + 1][hl]) << 16);
    u32 p1 = (u32)f2bf(tile[cq + 2][hl]) | ((u32)f2bf(tile[cq + 3][hl]) << 16);
    u32 p2 = (u32)f2bf(tile[cq + 4][hl]) | ((u32)f2bf(tile[cq + 5][hl]) << 16);
    u32 p3 = (u32)f2bf(tile[cq + 6][hl]) | ((u32)f2bf(tile[cq + 7][hl]) << 16);
    u32 p4 = (u32)f2bf(tile[cq + 8][hl]) | ((u32)f2bf(tile[cq + 9][hl]) << 16);
    u32 p5 = (u32)f2bf(tile[cq +10][hl]) | ((u32)f2bf(tile[cq +11][hl]) << 16);
    u32 p6 = (u32)f2bf(tile[cq +12][hl]) | ((u32)f2bf(tile[cq +13][hl]) << 16);
    u32 p7 = (u32)f2bf(tile[cq +14][hl]) | ((u32)f2bf(tile[cq +15][hl]) << 16);
    u16* dst = xT + ((size_t)b * HWW + h0 + hl) * CC + c0 + cq;
    *(uint4*)(dst)     = make_uint4(p0, p1, p2, p3);
    *(uint4*)(dst + 8) = make_uint4(p4, p5, p6, p7);
}

// ========== Kernel A2: c_adj[b][c] = mean ==========

__global__ __launch_bounds__(256) void reduce_kernel(const float* __restrict__ partial,
                                                     float* __restrict__ c_adj) {
    int b = blockIdx.x;
    int c = threadIdx.x;
    float s = 0.f;
#pragma unroll 8
    for (int hx = 0; hx < 64; ++hx)
        s += partial[((size_t)b * 64 + hx) * CC + c];
    c_adj[b * CC + c] = s * (1.0f / HWW);
}

// ========== Kernel B: w_bf16[b,i,j] = bf16( adj[i,j] * (1 - |tanh(d/2)|) ) ==========
// s = ||sigmoid(d)-0.5|-0.5|*2 is symmetric in d (sigmoid(-d)-0.5 = -(sigmoid(d)-0.5)),
// and equals 2t/(1+t) with t = exp(-|d|).

__global__ __launch_bounds__(256) void weight_bf16_kernel(const float* __restrict__ c_adj,
                                                          const float* __restrict__ adj,
                                                          u16* __restrict__ wb) {
    int idx = blockIdx.x * 256 + threadIdx.x;
    int b = idx >> 16;
    int rem = idx & 65535;
    int i = rem >> 8;
    int j = rem & 255;
    float d = c_adj[b * CC + j] - c_adj[b * CC + i];
    float tt = expf(-fabsf(d));
    float s = 2.f * tt / (1.f + tt);
    wb[idx] = f2bf(adj[i * CC + j] * s);
}

// ========== Kernel C: MFMA GEMM + para + relu (verified R3 structure) ==========
#define GBM 128
#define GBN 128
#define GBK 32

__global__ __launch_bounds__(256) void mfma_gemm_kernel(const u16* __restrict__ wb,
                                                        const u16* __restrict__ xT,
                                                        const float* __restrict__ para,
                                                        float* __restrict__ out) {
    int b  = blockIdx.z;
    int i0 = blockIdx.y * GBM;
    int n0 = blockIdx.x * GBN;
    const u16* wB = wb + (size_t)b * CC * CC;     // [i][k], k contiguous
    const u16* xB = xT + (size_t)b * HWW * CC;    // [n][k], k contiguous

    __shared__ u16 lds[2][2][4096];               // [buf][A/B][128 rows x 32 k]

    int t    = threadIdx.x;
    int lane = t & 63;
    int wid  = t >> 6;
    int wr   = wid >> 1;
    int wc   = wid & 1;

    f32x4 acc[4][4] = {};

    int r0  = t >> 2;          // 0..63
    int c0q = t & 3;
    int cs  = c0q ^ ((r0 >> 1) & 3);              // bijective in-row chunk swizzle
    int e0 = r0 * 32 + 8 * cs;
    int e1 = (r0 + 64) * 32 + 8 * cs;

    const u16* gA0 = wB + (size_t)(i0 + r0) * CC + 8 * c0q;
    const u16* gA1 = wB + (size_t)(i0 + r0 + 64) * CC + 8 * c0q;
    const u16* gB0 = xB + (size_t)(n0 + r0) * CC + 8 * c0q;
    const u16* gB1 = xB + (size_t)(n0 + r0 + 64) * CC + 8 * c0q;

    uint4 ra0, ra1, rb0, rb1;

#define LOADT(kk) { ra0 = *(const uint4*)(gA0 + (kk)); ra1 = *(const uint4*)(gA1 + (kk)); \
                    rb0 = *(const uint4*)(gB0 + (kk)); rb1 = *(const uint4*)(gB1 + (kk)); }
#define STORET(bf) { *(uint4*)&lds[bf][0][e0] = ra0; *(uint4*)&lds[bf][0][e1] = ra1; \
                     *(uint4*)&lds[bf][1][e0] = rb0; *(uint4*)&lds[bf][1][e1] = rb1; }

    LOADT(0);
    STORET(0);
    __syncthreads();

    int lrow = lane & 15;
    int kc   = lane >> 4;
    int swz  = (lrow >> 1) & 3;

#pragma unroll 1
    for (int kt = 0; kt < 8; ++kt) {
        int cur = kt & 1;
        if (kt < 7) LOADT((kt + 1) * GBK);

        bf16x8 af[4], bfr[4];
#pragma unroll
        for (int m = 0; m < 4; ++m) {
            int row = wr * 64 + m * 16 + lrow;
            af[m] = *(bf16x8*)&lds[cur][0][row * 32 + 8 * (kc ^ swz)];
        }
#pragma unroll
        for (int q = 0; q < 4; ++q) {
            int row = wc * 64 + q * 16 + lrow;
            bfr[q] = *(bf16x8*)&lds[cur][1][row * 32 + 8 * (kc ^ swz)];
        }
#pragma unroll
        for (int m = 0; m < 4; ++m)
#pragma unroll
            for (int q = 0; q < 4; ++q)
                acc[m][q] = __builtin_amdgcn_mfma_f32_16x16x32_bf16(af[m], bfr[q], acc[m][q], 0, 0, 0);

        if (kt < 7) STORET(cur ^ 1);
        __syncthreads();
    }
#undef LOADT
#undef STORET

    // epilogue: D mapping col=lane&15, row=4*(lane>>4)+r  [m89-verified]
    int dcol = lane & 15;
    int drow = 4 * (lane >> 4);
#pragma unroll
    for (int m = 0; m < 4; ++m) {
#pragma unroll
        for (int q = 0; q < 4; ++q) {
            int i = i0 + wr * 64 + m * 16 + drow;
            int n = n0 + wc * 64 + q * 16 + dcol;
#pragma unroll
            for (int r = 0; r < 4; ++r) {
                float pv = para[(size_t)(i + r) * HWW + n];
                float o = fmaxf(acc[m][q][r] * pv, 0.f);
                __builtin_nontemporal_store(o, &out[((size_t)b * CC + i + r) * HWW + n]);
            }
        }
    }
}

// ================= FALLBACK (fp32 path, used if ws too small) =================

__global__ __launch_bounds__(256) void avgpool_kernel(const float* __restrict__ x,
                                                      float* __restrict__ c_adj) {
    int bc = blockIdx.x;
    const float4* p4 = (const float4*)(x + (size_t)bc * HWW);
    int t = threadIdx.x;
    float sum = 0.f;
#pragma unroll
    for (int m = 0; m < 4; ++m) {
        float4 v = p4[t + 256 * m];
        sum += v.x + v.y + v.z + v.w;
    }
#pragma unroll
    for (int off = 32; off > 0; off >>= 1)
        sum += __shfl_down(sum, off, 64);
    __shared__ float partial[4];
    int wid = t >> 6, lane = t & 63;
    if (lane == 0) partial[wid] = sum;
    __syncthreads();
    if (t == 0)
        c_adj[bc] = (partial[0] + partial[1] + partial[2] + partial[3]) * (1.0f / HWW);
}

__global__ __launch_bounds__(256) void weight_kernel(const float* __restrict__ c_adj,
                                                     const float* __restrict__ adj,
                                                     float* __restrict__ w) {
    int idx = blockIdx.x * 256 + threadIdx.x;
    int b = idx >> 16, rem = idx & 65535, i = rem >> 8, j = rem & 255;
    float d = c_adj[b * CC + j] - c_adj[b * CC + i];
    float tt = expf(-fabsf(d));
    w[idx] = adj[i * CC + j] * 2.f * tt / (1.f + tt);
}

#define BM 64
#define BN 64
#define BK 16
__global__ __launch_bounds__(256) void gemm_kernel(const float* __restrict__ w,
                                                   const float* __restrict__ x,
                                                   const float* __restrict__ para,
                                                   float* __restrict__ out) {
    int b = blockIdx.z, i0 = blockIdx.y * BM, n0 = blockIdx.x * BN;
    const float* wB = w + (size_t)b * CC * CC;
    const float* xB = x + (size_t)b * CC * HWW;
    float* outB = out + (size_t)b * CC * HWW;
    __shared__ float wT[BK][68];
    __shared__ float xS[BK][BN];
    int t = threadIdx.x, tr = t >> 4, tc = t & 15;
    float acc[4][4] = {};
    for (int k0 = 0; k0 < CC; k0 += BK) {
        {
            int i = t >> 2, kq = (t & 3) * 4;
            float4 v = *(const float4*)&wB[(size_t)(i0 + i) * CC + k0 + kq];
            wT[kq + 0][i] = v.x; wT[kq + 1][i] = v.y; wT[kq + 2][i] = v.z; wT[kq + 3][i] = v.w;
        }
        {
            int k = t >> 4, nq = (t & 15) * 4;
            *(float4*)&xS[k][nq] = *(const float4*)&xB[(size_t)(k0 + k) * HWW + n0 + nq];
        }
        __syncthreads();
#pragma unroll
        for (int k = 0; k < BK; ++k) {
            float wv[4], xv[4];
            *(float4*)wv = *(const float4*)&wT[k][tr * 4];
            *(float4*)xv = *(const float4*)&xS[k][tc * 4];
#pragma unroll
            for (int r = 0; r < 4; ++r)
#pragma unroll
                for (int q = 0; q < 4; ++q)
                    acc[r][q] = fmaf(wv[r], xv[q], acc[r][q]);
        }
        __syncthreads();
    }
#pragma unroll
    for (int r = 0; r < 4; ++r) {
        int i = i0 + tr * 4 + r, n = n0 + tc * 4;
        float4 pv = *(const float4*)&para[(size_t)i * HWW + n];
        float4 o;
        o.x = fmaxf(acc[r][0] * pv.x, 0.f);
        o.y = fmaxf(acc[r][1] * pv.y, 0.f);
        o.z = fmaxf(acc[r][2] * pv.z, 0.f);
        o.w = fmaxf(acc[r][3] * pv.w, 0.f);
        *(float4*)&outB[(size_t)i * HWW + n] = o;
    }
}

// ================= launch =================

extern "C" void kernel_launch(void* const* d_in, const int* in_sizes, int n_in,
                              void* d_out, int out_size, void* d_ws, size_t ws_size,
                              hipStream_t stream) {
    const float* x    = (const float*)d_in[0];
    const float* adj  = (const float*)d_in[1];
    const float* para = (const float*)d_in[2];
    float* out = (float*)d_out;

    const size_t XT_BYTES = (size_t)BB * HWW * CC * 2;       // 67,108,864
    const size_t WB_BYTES = (size_t)BB * CC * CC * 2;        //  4,194,304 (aliases partial)
    const size_t CA_BYTES = (size_t)BB * CC * 4;             //     32,768
    const size_t REQ = XT_BYTES + WB_BYTES + CA_BYTES;

    if (ws_size >= REQ) {
        u16*   xT      = (u16*)d_ws;
        u16*   wbuf    = (u16*)((char*)d_ws + XT_BYTES);
        float* partial = (float*)((char*)d_ws + XT_BYTES);   // 2 MB, dead before wbuf written
        float* c_adj   = (float*)((char*)d_ws + XT_BYTES + WB_BYTES);

        dim3 gA(HWW / 64, CC / 64, BB);
        pool_transpose_kernel<<<gA, 256, 0, stream>>>(x, xT, partial);
        reduce_kernel<<<BB, 256, 0, stream>>>(partial, c_adj);
        weight_bf16_kernel<<<(BB * CC * CC) / 256, 256, 0, stream>>>(c_adj, adj, wbuf);
        dim3 gC(HWW / GBN, CC / GBM, BB);
        mfma_gemm_kernel<<<gC, 256, 0, stream>>>(wbuf, xT, para, out);
    } else {
        float* c_adj = (float*)d_ws;
        float* w     = (float*)d_ws + (BB * CC);
        avgpool_kernel<<<BB * CC, 256, 0, stream>>>(x, c_adj);
        weight_kernel<<<(BB * CC * CC) / 256, 256, 0, stream>>>(c_adj, adj, w);
        dim3 grid(HWW / BN, CC / BM, BB);
        gemm_kernel<<<grid, 256, 0, stream>>>(w, x, para, out);
    }
}

// Round 5
// 93.277 us; speedup vs baseline: 2.5613x; 1.0374x over previous
//
#include <hip/hip_runtime.h>
#include <math.h>

#define BB 32
#define CC 256
#define HWW 4096

typedef unsigned short u16;
typedef unsigned int u32;

typedef __attribute__((ext_vector_type(8))) short bf16x8;
typedef __attribute__((ext_vector_type(4))) float f32x4;

__device__ inline u16 f2bf(float f) {
    u32 u = __float_as_uint(f);
    u32 r = (u + 0x7fff + ((u >> 16) & 1)) >> 16;   // RNE
    return (u16)r;
}

// ========== Kernel A: avg-pool partials + transpose x -> xT[b][n][k] bf16 ==========

__global__ __launch_bounds__(256) void pool_transpose_kernel(const float* __restrict__ x,
                                                             u16* __restrict__ xT,
                                                             float* __restrict__ partial) {
    int b  = blockIdx.z;
    int c0 = blockIdx.y * 64;
    int h0 = blockIdx.x * 64;
    const float* xB = x + (size_t)b * CC * HWW;

    __shared__ float tile[64][65];
    __shared__ float psum[64];
    int t  = threadIdx.x;
    int cl = t >> 4;            // 0..15
    int h4 = (t & 15) * 4;

#pragma unroll
    for (int m = 0; m < 4; ++m) {
        int c = cl + 16 * m;
        float4 v = *(const float4*)&xB[(size_t)(c0 + c) * HWW + h0 + h4];
        tile[c][h4 + 0] = v.x;
        tile[c][h4 + 1] = v.y;
        tile[c][h4 + 2] = v.z;
        tile[c][h4 + 3] = v.w;
        float s = v.x + v.y + v.z + v.w;
#pragma unroll
        for (int off = 8; off > 0; off >>= 1)
            s += __shfl_down(s, off, 16);
        if ((t & 15) == 0) psum[c] = s;
    }
    __syncthreads();

    if (t < 64)
        partial[((size_t)b * 64 + blockIdx.x) * CC + c0 + t] = psum[t];

    int hl = t >> 2;            // 0..63
    int cq = (t & 3) * 16;      // 0,16,32,48
    u32 p0 = (u32)f2bf(tile[cq + 0][hl]) | ((u32)f2bf(tile[cq + 1][hl]) << 16);
    u32 p1 = (u32)f2bf(tile[cq + 2][hl]) | ((u32)f2bf(tile[cq + 3][hl]) << 16);
    u32 p2 = (u32)f2bf(tile[cq + 4][hl]) | ((u32)f2bf(tile[cq + 5][hl]) << 16);
    u32 p3 = (u32)f2bf(tile[cq + 6][hl]) | ((u32)f2bf(tile[cq + 7][hl]) << 16);
    u32 p4 = (u32)f2bf(tile[cq + 8][hl]) | ((u32)f2bf(tile[cq + 9][hl]) << 16);
    u32 p5 = (u32)f2bf(tile[cq +10][hl]) | ((u32)f2bf(tile[cq +11][hl]) << 16);
    u32 p6 = (u32)f2bf(tile[cq +12][hl]) | ((u32)f2bf(tile[cq +13][hl]) << 16);
    u32 p7 = (u32)f2bf(tile[cq +14][hl]) | ((u32)f2bf(tile[cq +15][hl]) << 16);
    u16* dst = xT + ((size_t)b * HWW + h0 + hl) * CC + c0 + cq;
    *(uint4*)(dst)     = make_uint4(p0, p1, p2, p3);
    *(uint4*)(dst + 8) = make_uint4(p4, p5, p6, p7);
}

// ========== Kernel B: fused reduce + weight.  grid = BB*8, block = (b, 32-row i-chunk)
// s = ||sigmoid(d)-0.5|-0.5|*2 = 2t/(1+t), t=exp(-|d|)  (symmetric; symmetrization is no-op)

__global__ __launch_bounds__(256) void reduce_weight_kernel(const float* __restrict__ partial,
                                                            const float* __restrict__ adj,
                                                            u16* __restrict__ wb) {
    int b  = blockIdx.x >> 3;
    int ic = (blockIdx.x & 7) * 32;
    int t  = threadIdx.x;

    __shared__ float ca[CC];
    float s = 0.f;
#pragma unroll 8
    for (int hx = 0; hx < 64; ++hx)
        s += partial[((size_t)b * 64 + hx) * CC + t];
    ca[t] = s * (1.0f / HWW);
    __syncthreads();

    u16* wB = wb + (size_t)b * CC * CC;
    float cj = ca[t];
#pragma unroll 4
    for (int r = 0; r < 32; ++r) {
        int i = ic + r;
        float d  = cj - ca[i];
        float tt = __expf(-fabsf(d));
        float sv = 2.f * tt / (1.f + tt);
        wB[(size_t)i * CC + t] = f2bf(adj[i * CC + t] * sv);
    }
}

// ========== Kernel C: MFMA GEMM + para + relu ==========
// 128x128 tile, BK=32, 4 waves (2x2), 4x4 frags of 16x16x32 per wave.
// Staging via global_load_lds width=16: LDS dest LINEAR (lane t -> element t*8),
// swizzle applied to the GLOBAL source chunk (c0q ^ ((row>>1)&3)) — same involution
// as the ds_read side, so content map matches the verified R4 kernel exactly.
#define GBM 128
#define GBN 128
#define GBK 32

__global__ __launch_bounds__(256) void mfma_gemm_kernel(const u16* __restrict__ wb,
                                                        const u16* __restrict__ xT,
                                                        const float* __restrict__ para,
                                                        float* __restrict__ out) {
    int b  = blockIdx.z;
    int i0 = blockIdx.y * GBM;
    int n0 = blockIdx.x * GBN;
    const u16* wB = wb + (size_t)b * CC * CC;     // [i][k], k contiguous
    const u16* xB = xT + (size_t)b * HWW * CC;    // [n][k], k contiguous

    __shared__ u16 lds[2][2][4096];               // [buf][A/B][128 rows x 32 k]

    int t    = threadIdx.x;
    int lane = t & 63;
    int wid  = t >> 6;
    int wid_s = __builtin_amdgcn_readfirstlane(wid);
    int wr   = wid >> 1;
    int wc   = wid & 1;

    f32x4 acc[4][4] = {};

    // staging geometry: thread t <-> (row r0 = t>>2, chunk c0q = t&3); also row r0+64
    int r0  = t >> 2;
    int c0q = t & 3;
    int csq = c0q ^ ((r0 >> 1) & 3);              // pre-swizzled GLOBAL chunk (same for r0+64)

    const u16* gA0 = wB + (size_t)(i0 + r0) * CC + 8 * csq;
    const u16* gA1 = wB + (size_t)(i0 + r0 + 64) * CC + 8 * csq;
    const u16* gB0 = xB + (size_t)(n0 + r0) * CC + 8 * csq;
    const u16* gB1 = xB + (size_t)(n0 + r0 + 64) * CC + 8 * csq;

    // wave-uniform LDS dest bases (elements): wave covers 512 elems (1KB) per call
#define GLDS(ptr, dst) __builtin_amdgcn_global_load_lds( \
        (const __attribute__((address_space(1))) void*)(ptr), \
        (__attribute__((address_space(3))) void*)(dst), 16, 0, 0)

#define STAGE(kk, bf) { \
        GLDS(gA0 + (kk), &lds[bf][0][wid_s * 512]); \
        GLDS(gA1 + (kk), &lds[bf][0][2048 + wid_s * 512]); \
        GLDS(gB0 + (kk), &lds[bf][1][wid_s * 512]); \
        GLDS(gB1 + (kk), &lds[bf][1][2048 + wid_s * 512]); }

    STAGE(0, 0);
    __syncthreads();

    int lrow = lane & 15;
    int kc   = lane >> 4;
    int swz  = (lrow >> 1) & 3;

#pragma unroll 1
    for (int kt = 0; kt < 8; ++kt) {
        int cur = kt & 1;
        if (kt < 7) STAGE((kt + 1) * GBK, cur ^ 1);

        bf16x8 af[4], bfr[4];
#pragma unroll
        for (int m = 0; m < 4; ++m) {
            int row = wr * 64 + m * 16 + lrow;
            af[m] = *(bf16x8*)&lds[cur][0][row * 32 + 8 * (kc ^ swz)];
        }
#pragma unroll
        for (int q = 0; q < 4; ++q) {
            int row = wc * 64 + q * 16 + lrow;
            bfr[q] = *(bf16x8*)&lds[cur][1][row * 32 + 8 * (kc ^ swz)];
        }
#pragma unroll
        for (int m = 0; m < 4; ++m)
#pragma unroll
            for (int q = 0; q < 4; ++q)
                acc[m][q] = __builtin_amdgcn_mfma_f32_16x16x32_bf16(af[m], bfr[q], acc[m][q], 0, 0, 0);

        __syncthreads();   // drains vmcnt(0): next buf complete; cur reads done for all waves
    }
#undef STAGE
#undef GLDS

    // epilogue: D mapping col=lane&15, row=4*(lane>>4)+r  [m89-verified]
    int dcol = lane & 15;
    int drow = 4 * (lane >> 4);
#pragma unroll
    for (int m = 0; m < 4; ++m) {
#pragma unroll
        for (int q = 0; q < 4; ++q) {
            int i = i0 + wr * 64 + m * 16 + drow;
            int n = n0 + wc * 64 + q * 16 + dcol;
#pragma unroll
            for (int r = 0; r < 4; ++r) {
                float pv = para[(size_t)(i + r) * HWW + n];
                float o = fmaxf(acc[m][q][r] * pv, 0.f);
                __builtin_nontemporal_store(o, &out[((size_t)b * CC + i + r) * HWW + n]);
            }
        }
    }
}

// ================= FALLBACK (fp32 path, used if ws too small) =================

__global__ __launch_bounds__(256) void avgpool_kernel(const float* __restrict__ x,
                                                      float* __restrict__ c_adj) {
    int bc = blockIdx.x;
    const float4* p4 = (const float4*)(x + (size_t)bc * HWW);
    int t = threadIdx.x;
    float sum = 0.f;
#pragma unroll
    for (int m = 0; m < 4; ++m) {
        float4 v = p4[t + 256 * m];
        sum += v.x + v.y + v.z + v.w;
    }
#pragma unroll
    for (int off = 32; off > 0; off >>= 1)
        sum += __shfl_down(sum, off, 64);
    __shared__ float partial[4];
    int wid = t >> 6, lane = t & 63;
    if (lane == 0) partial[wid] = sum;
    __syncthreads();
    if (t == 0)
        c_adj[bc] = (partial[0] + partial[1] + partial[2] + partial[3]) * (1.0f / HWW);
}

__global__ __launch_bounds__(256) void weight_kernel(const float* __restrict__ c_adj,
                                                     const float* __restrict__ adj,
                                                     float* __restrict__ w) {
    int idx = blockIdx.x * 256 + threadIdx.x;
    int b = idx >> 16, rem = idx & 65535, i = rem >> 8, j = rem & 255;
    float d = c_adj[b * CC + j] - c_adj[b * CC + i];
    float tt = expf(-fabsf(d));
    w[idx] = adj[i * CC + j] * 2.f * tt / (1.f + tt);
}

#define BM 64
#define BN 64
#define BK 16
__global__ __launch_bounds__(256) void gemm_kernel(const float* __restrict__ w,
                                                   const float* __restrict__ x,
                                                   const float* __restrict__ para,
                                                   float* __restrict__ out) {
    int b = blockIdx.z, i0 = blockIdx.y * BM, n0 = blockIdx.x * BN;
    const float* wB = w + (size_t)b * CC * CC;
    const float* xB = x + (size_t)b * CC * HWW;
    float* outB = out + (size_t)b * CC * HWW;
    __shared__ float wT[BK][68];
    __shared__ float xS[BK][BN];
    int t = threadIdx.x, tr = t >> 4, tc = t & 15;
    float acc[4][4] = {};
    for (int k0 = 0; k0 < CC; k0 += BK) {
        {
            int i = t >> 2, kq = (t & 3) * 4;
            float4 v = *(const float4*)&wB[(size_t)(i0 + i) * CC + k0 + kq];
            wT[kq + 0][i] = v.x; wT[kq + 1][i] = v.y; wT[kq + 2][i] = v.z; wT[kq + 3][i] = v.w;
        }
        {
            int k = t >> 4, nq = (t & 15) * 4;
            *(float4*)&xS[k][nq] = *(const float4*)&xB[(size_t)(k0 + k) * HWW + n0 + nq];
        }
        __syncthreads();
#pragma unroll
        for (int k = 0; k < BK; ++k) {
            float wv[4], xv[4];
            *(float4*)wv = *(const float4*)&wT[k][tr * 4];
            *(float4*)xv = *(const float4*)&xS[k][tc * 4];
#pragma unroll
            for (int r = 0; r < 4; ++r)
#pragma unroll
                for (int q = 0; q < 4; ++q)
                    acc[r][q] = fmaf(wv[r], xv[q], acc[r][q]);
        }
        __syncthreads();
    }
#pragma unroll
    for (int r = 0; r < 4; ++r) {
        int i = i0 + tr * 4 + r, n = n0 + tc * 4;
        float4 pv = *(const float4*)&para[(size_t)i * HWW + n];
        float4 o;
        o.x = fmaxf(acc[r][0] * pv.x, 0.f);
        o.y = fmaxf(acc[r][1] * pv.y, 0.f);
        o.z = fmaxf(acc[r][2] * pv.z, 0.f);
        o.w = fmaxf(acc[r][3] * pv.w, 0.f);
        *(float4*)&outB[(size_t)i * HWW + n] = o;
    }
}

// ================= launch =================

extern "C" void kernel_launch(void* const* d_in, const int* in_sizes, int n_in,
                              void* d_out, int out_size, void* d_ws, size_t ws_size,
                              hipStream_t stream) {
    const float* x    = (const float*)d_in[0];
    const float* adj  = (const float*)d_in[1];
    const float* para = (const float*)d_in[2];
    float* out = (float*)d_out;

    const size_t XT_BYTES = (size_t)BB * HWW * CC * 2;       // 67,108,864
    const size_t WB_BYTES = (size_t)BB * CC * CC * 2;        //  4,194,304
    const size_t PT_BYTES = (size_t)BB * 64 * CC * 4;        //  2,097,152 (NOT aliased with wb)
    const size_t REQ = XT_BYTES + WB_BYTES + PT_BYTES;

    if (ws_size >= REQ) {
        u16*   xT      = (u16*)d_ws;
        u16*   wbuf    = (u16*)((char*)d_ws + XT_BYTES);
        float* partial = (float*)((char*)d_ws + XT_BYTES + WB_BYTES);

        dim3 gA(HWW / 64, CC / 64, BB);
        pool_transpose_kernel<<<gA, 256, 0, stream>>>(x, xT, partial);
        reduce_weight_kernel<<<BB * 8, 256, 0, stream>>>(partial, adj, wbuf);
        dim3 gC(HWW / GBN, CC / GBM, BB);
        mfma_gemm_kernel<<<gC, 256, 0, stream>>>(wbuf, xT, para, out);
    } else {
        float* c_adj = (float*)d_ws;
        float* w     = (float*)d_ws + (BB * CC);
        avgpool_kernel<<<BB * CC, 256, 0, stream>>>(x, c_adj);
        weight_kernel<<<(BB * CC * CC) / 256, 256, 0, stream>>>(c_adj, adj, w);
        dim3 grid(HWW / BN, CC / BM, BB);
        gemm_kernel<<<grid, 256, 0, stream>>>(w, x, para, out);
    }
}